// Round 8
// baseline (813.055 us; speedup 1.0000x reference)
//
#include <hip/hip_runtime.h>
#include <hip/hip_bf16.h>
#include <math.h>

#define B_ROWS 16384
#define DM 512
#define DFF 2048
#define DOUT 256
#define EPSV 1e-5f

typedef __hip_bfloat16 bf16;
typedef __attribute__((ext_vector_type(8))) short short8;
typedef __attribute__((ext_vector_type(4))) float f32x4;

__device__ __forceinline__ float gelu_f(float x) {
    return 0.5f * x * (1.0f + erff(x * 0.70710678118654752f));
}

__device__ __forceinline__ float bf2f(short s) {
    return __uint_as_float(((unsigned int)(unsigned short)s) << 16);
}

__device__ __forceinline__ void gload16(const void* g, void* l) {
    __builtin_amdgcn_global_load_lds((const __attribute__((address_space(1))) void*)g,
                                     (__attribute__((address_space(3))) void*)l, 16, 0, 0);
}

// bijective XCD swizzle; requires nwg % 8 == 0 (all our grids satisfy this)
__device__ __forceinline__ int xcd_swz(int bid, int nwg) {
    const int cpx = nwg >> 3;
    return (bid & 7) * cpx + (bid >> 3);
}

// ============================================================================
// 256x256 8-phase pipelined GEMM (T2 swizzle + T3/T4 counted vmcnt + T5 setprio)
// C = gelu(A @ BT^T + bias) -> bf16. M%256==0, N%256==0, K%64==0, K>=128.
// 512 threads / 8 waves (2M x 4N); per-wave 128x64 out; BK=64 as 2 k-halves.
// LDS 128KB: A,B each [2 buf][2 khalf][256 rows][32 k] bf16, XOR-swizzled chunks.
// Race-freedom: every phase's staging unit targets a region whose last reader
// finished before a barrier that precedes the issue (argued per-phase below).
// vmcnt(4) once per tile (= allow 2 newest 16KB units in flight).
// ============================================================================
#define SBAR() do { __builtin_amdgcn_sched_barrier(0); \
                    __builtin_amdgcn_s_barrier();      \
                    __builtin_amdgcn_sched_barrier(0); } while (0)

__global__ __launch_bounds__(512, 2)
void gemm256_gelu_kernel(const bf16* __restrict__ A, const bf16* __restrict__ BT,
                         const float* __restrict__ bias, bf16* __restrict__ Cb,
                         int M, int N, int K)
{
    __shared__ __align__(16) bf16 lds[65536];   // 128 KB
    bf16* lA = lds;            // 32768 elems
    bf16* lB = lds + 32768;

    const int t    = threadIdx.x;
    const int lane = t & 63;
    const int w    = t >> 6;          // 0..7
    const int wm   = w >> 2, wn = w & 3;
    const int fr   = lane & 15, kg = lane >> 4;

    const int bid = xcd_swz(blockIdx.y * gridDim.x + blockIdx.x, gridDim.x * gridDim.y);
    const int bx = bid % gridDim.x, by = bid / gridDim.x;
    const long bm = (long)by * 256;
    const long bn = (long)bx * 256;

    // staging decomposition: 512 threads x 16B = 8KB/issue; unit(16KB)=2 issues
    const int srow = t >> 2;          // 0..127
    const int skc  = t & 3;           // 16B chunk within k-half

    // unit = (operand, tile KT, khalf KH): rows j*128+srow, linear LDS dest,
    // inverse-swizzled global source (rule #21: linear dest + inv-swz src + swz read)
#define STAGE_A(KT, KH) { const int b_ = (KT) & 1;                                         \
    _Pragma("unroll") for (int j = 0; j < 2; ++j) {                                        \
        const int lrow = j * 128 + srow;                                                   \
        gload16(A + (bm + lrow) * (long)K + (KT) * 64 + (KH) * 32                          \
                  + ((skc ^ ((lrow >> 1) & 3)) * 8),                                       \
                lA + b_ * 16384 + (KH) * 8192 + lrow * 32 + skc * 8); } }
#define STAGE_B(KT, KH) { const int b_ = (KT) & 1;                                         \
    _Pragma("unroll") for (int j = 0; j < 2; ++j) {                                        \
        const int lrow = j * 128 + srow;                                                   \
        gload16(BT + (bn + lrow) * (long)K + (KT) * 64 + (KH) * 32                         \
                  + ((skc ^ ((lrow >> 1) & 3)) * 8),                                       \
                lB + b_ * 16384 + (KH) * 8192 + lrow * 32 + skc * 8); } }

    // swizzled fragment reads (row varies per lane via fr -> 2-way banks = free)
#define LDA(BUF, KS, AM) (*(const short8*)(lA + (BUF) * 16384 + (KS) * 8192               \
        + (wm * 128 + (AM) * 16 + fr) * 32                                                 \
        + ((kg ^ (((wm * 128 + (AM) * 16 + fr) >> 1) & 3)) * 8)))
#define LDB(BUF, KS, AN) (*(const short8*)(lB + (BUF) * 16384 + (KS) * 8192               \
        + (wn * 64 + (AN) * 16 + fr) * 32                                                  \
        + ((kg ^ (((wn * 64 + (AN) * 16 + fr) >> 1) & 3)) * 8)))

#define MFMA_PHASE(AMBASE)                                                                 \
    __builtin_amdgcn_s_setprio(1);                                                         \
    _Pragma("unroll") for (int i_ = 0; i_ < 4; ++i_) {                                     \
        _Pragma("unroll") for (int an_ = 0; an_ < 4; ++an_)                                \
            acc[(AMBASE) + i_][an_] = __builtin_amdgcn_mfma_f32_16x16x32_bf16(             \
                afr[i_], bfr[an_], acc[(AMBASE) + i_][an_], 0, 0, 0); }                    \
    __builtin_amdgcn_s_setprio(0);

    f32x4 acc[8][4];
#pragma unroll
    for (int i = 0; i < 8; i++)
#pragma unroll
        for (int j = 0; j < 4; j++) acc[i][j] = (f32x4){0.f, 0.f, 0.f, 0.f};

    const int NT = K >> 6;   // K/64 tiles (NT >= 2 required)

    // prologue: tile0 fully (4 units, oldest first), then tile1 k-half0 (2 units)
    STAGE_A(0, 0); STAGE_B(0, 0); STAGE_A(0, 1); STAGE_B(0, 1);
    STAGE_A(1, 0); STAGE_B(1, 0);
    asm volatile("s_waitcnt vmcnt(4)" ::: "memory");  // tile0 landed; tile1-kh0 may fly
    SBAR();

    for (int T = 0; T < NT; ++T) {
        const int buf = T & 1;
        short8 afr[4], bfr[4];

        // ---- ph0: ks0, am0-3. Stage A-kh1(T+1) -> buf^1 kh1 (last read: T-1 ph2/ph3,
        //      sealed by T-1 ph3 barrier). Reads buf kh0 (landed per vmcnt at T-1 ph3).
#pragma unroll
        for (int an = 0; an < 4; ++an) bfr[an] = LDB(buf, 0, an);
#pragma unroll
        for (int i = 0; i < 4; ++i) afr[i] = LDA(buf, 0, i);
        if (T + 1 < NT) STAGE_A(T + 1, 1);
        SBAR();
        MFMA_PHASE(0);
        SBAR();

        // ---- ph1: ks0, am4-7 (bfr reused). Stage B-kh1(T+1) -> buf^1 (same arg as ph0).
#pragma unroll
        for (int i = 0; i < 4; ++i) afr[i] = LDA(buf, 0, 4 + i);
        if (T + 1 < NT) STAGE_B(T + 1, 1);
        SBAR();
        MFMA_PHASE(4);
        SBAR();

        // ---- ph2: ks1, am0-3. Stage A-kh0(T+2) -> buf kh0: its last readers were
        //      ph0/ph1 of THIS tile, sealed by ph1's closing barrier above.
#pragma unroll
        for (int an = 0; an < 4; ++an) bfr[an] = LDB(buf, 1, an);
#pragma unroll
        for (int i = 0; i < 4; ++i) afr[i] = LDA(buf, 1, i);
        if (T + 2 < NT) STAGE_A(T + 2, 0);
        SBAR();
        MFMA_PHASE(0);
        SBAR();

        // ---- ph3: ks1, am4-7. Stage B-kh0(T+2) (same arg as ph2). Then the once-per-
        //      tile vmcnt(4): all but the 2 newest units (kh0 of T+2) must have landed
        //      => tile T+1 fully resident before its ph0 reads after this barrier.
#pragma unroll
        for (int i = 0; i < 4; ++i) afr[i] = LDA(buf, 1, 4 + i);
        if (T + 2 < NT) STAGE_B(T + 2, 0);
        SBAR();
        MFMA_PHASE(4);
        asm volatile("s_waitcnt vmcnt(4)" ::: "memory");
        SBAR();
    }
    asm volatile("s_waitcnt vmcnt(0)" ::: "memory");  // drain any stragglers

    // epilogue: row = bm + wm*128 + am*16 + kg*4 + r ; col = bn + wn*64 + an*16 + fr
#pragma unroll
    for (int am = 0; am < 8; ++am) {
        const long row0 = bm + wm * 128 + am * 16 + kg * 4;
#pragma unroll
        for (int an = 0; an < 4; ++an) {
            const long col = bn + wn * 64 + an * 16 + fr;
            const float bv_ = bias[col];
#pragma unroll
            for (int r = 0; r < 4; ++r) {
                const float v = gelu_f(acc[am][an][r] + bv_);
                Cb[(row0 + r) * (long)N + col] = __float2bfloat16(v);
            }
        }
    }
#undef STAGE_A
#undef STAGE_B
#undef LDA
#undef LDB
#undef MFMA_PHASE
}

// ============================================================================
// 128x128 2-phase GEMM (verified) — used for N=512 / small shapes
// ============================================================================
template<bool GELU, bool OUTF, bool OUTB>
__global__ __launch_bounds__(256, 2)
void gemm_kernel(const bf16* __restrict__ A, const bf16* __restrict__ BT,
                 const float* __restrict__ bias,
                 float* __restrict__ Cf, bf16* __restrict__ Cb,
                 int M, int N, int K)
{
    __shared__ __align__(16) bf16 lA[2][128 * 32];
    __shared__ __align__(16) bf16 lB[2][128 * 32];

    const int t    = threadIdx.x;
    const int lane = t & 63;
    const int w    = t >> 6;
    const int wr   = w >> 1, wc = w & 1;
    const int fr   = lane & 15, kg = lane >> 4;

    int bid = xcd_swz(blockIdx.y * gridDim.x + blockIdx.x, gridDim.x * gridDim.y);
    const int bx = bid % gridDim.x, by = bid / gridDim.x;
    const long bm = (long)by * 128;
    const long bn = (long)bx * 128;

    const int lr = t >> 2;
    const int lc = (t & 3) * 8;

    const bf16* Ag0 = A + (bm + lr) * (long)K + lc;
    const bf16* Ag1 = Ag0 + 64L * K;
    const bf16* Bg0 = BT + (bn + lr) * (long)K + lc;
    const bf16* Bg1 = Bg0 + 64L * K;

    f32x4 acc[4][4];
#pragma unroll
    for (int i = 0; i < 4; i++)
#pragma unroll
        for (int j = 0; j < 4; j++) acc[i][j] = (f32x4){0.f, 0.f, 0.f, 0.f};

    const int nk = K >> 5;

    gload16(Ag0, &lA[0][t * 8]);
    gload16(Ag1, &lA[0][2048 + t * 8]);
    gload16(Bg0, &lB[0][t * 8]);
    gload16(Bg1, &lB[0][2048 + t * 8]);
    Ag0 += 32; Ag1 += 32; Bg0 += 32; Bg1 += 32;
    __syncthreads();

    int cur = 0;
    for (int kt = 0; kt < nk; ++kt) {
        if (kt + 1 < nk) {
            const int nxt = cur ^ 1;
            gload16(Ag0, &lA[nxt][t * 8]);
            gload16(Ag1, &lA[nxt][2048 + t * 8]);
            gload16(Bg0, &lB[nxt][t * 8]);
            gload16(Bg1, &lB[nxt][2048 + t * 8]);
            Ag0 += 32; Ag1 += 32; Bg0 += 32; Bg1 += 32;
        }

        short8 af[4], bv[4];
#pragma unroll
        for (int m = 0; m < 4; m++)
            af[m] = *(const short8*)(&lA[cur][(wr * 64 + m * 16 + fr) * 32 + kg * 8]);
#pragma unroll
        for (int n = 0; n < 4; n++)
            bv[n] = *(const short8*)(&lB[cur][(wc * 64 + n * 16 + fr) * 32 + kg * 8]);
#pragma unroll
        for (int m = 0; m < 4; m++)
#pragma unroll
            for (int n = 0; n < 4; n++)
                acc[m][n] = __builtin_amdgcn_mfma_f32_16x16x32_bf16(af[m], bv[n], acc[m][n], 0, 0, 0);

        __syncthreads();
        cur ^= 1;
    }

#pragma unroll
    for (int m = 0; m < 4; m++) {
        const long row0 = bm + wr * 64 + m * 16 + kg * 4;
#pragma unroll
        for (int n = 0; n < 4; n++) {
            const long col = bn + wc * 64 + n * 16 + fr;
            const float bias_v = bias ? bias[col] : 0.0f;
#pragma unroll
            for (int r = 0; r < 4; r++) {
                float v = acc[m][n][r] + bias_v;
                if (GELU) v = gelu_f(v);
                const long idx = (row0 + r) * (long)N + col;
                if (OUTF) Cf[idx] = v;
                if (OUTB) Cb[idx] = __float2bfloat16(v);
            }
        }
    }
}

// LayerNorm over last dim (512). One wave per row, 4 rows/block.
template<bool HASADD, bool OUTF>
__global__ __launch_bounds__(256)
void ln_kernel(const float* __restrict__ x, const bf16* __restrict__ add,
               const float* __restrict__ g, const float* __restrict__ bb,
               float* __restrict__ outf, bf16* __restrict__ outb)
{
    const int w    = threadIdx.x >> 6;
    const int lane = threadIdx.x & 63;
    const long row = (long)blockIdx.x * 4 + w;
    const int c0   = lane * 8;

    const float* xr = x + row * DM + c0;
    float4 a0 = *(const float4*)xr;
    float4 a1 = *(const float4*)(xr + 4);
    float v[8] = {a0.x, a0.y, a0.z, a0.w, a1.x, a1.y, a1.z, a1.w};
    if (HASADD) {
        short8 ad = *(const short8*)(add + row * DM + c0);
#pragma unroll
        for (int j = 0; j < 8; j++) v[j] += bf2f(ad[j]);
    }
    float s = 0.f;
#pragma unroll
    for (int j = 0; j < 8; j++) s += v[j];
#pragma unroll
    for (int off = 32; off > 0; off >>= 1) s += __shfl_xor(s, off);
    const float mean = s * (1.0f / 512.0f);

    float q = 0.f;
#pragma unroll
    for (int j = 0; j < 8; j++) { v[j] -= mean; q += v[j] * v[j]; }
#pragma unroll
    for (int off = 32; off > 0; off >>= 1) q += __shfl_xor(q, off);
    const float rstd = rsqrtf(q * (1.0f / 512.0f) + EPSV);

    float4 g0 = *(const float4*)(g + c0);
    float4 g1 = *(const float4*)(g + c0 + 4);
    float4 b0 = *(const float4*)(bb + c0);
    float4 b1 = *(const float4*)(bb + c0 + 4);
    float y[8];
    y[0] = v[0] * rstd * g0.x + b0.x; y[1] = v[1] * rstd * g0.y + b0.y;
    y[2] = v[2] * rstd * g0.z + b0.z; y[3] = v[3] * rstd * g0.w + b0.w;
    y[4] = v[4] * rstd * g1.x + b1.x; y[5] = v[5] * rstd * g1.y + b1.y;
    y[6] = v[6] * rstd * g1.z + b1.z; y[7] = v[7] * rstd * g1.w + b1.w;

    if (OUTF) {
        float* orow = outf + row * DM + c0;
        *(float4*)orow       = make_float4(y[0], y[1], y[2], y[3]);
        *(float4*)(orow + 4) = make_float4(y[4], y[5], y[6], y[7]);
    }
    {
        bf16 tmpb[8];
#pragma unroll
        for (int j = 0; j < 8; j++) tmpb[j] = __float2bfloat16(y[j]);
        *(uint4*)(outb + row * DM + c0) = *(const uint4*)tmpb;
    }
}

// src (K x N fp32, batched) -> dst (N x K bf16, batched)
__global__ __launch_bounds__(256)
void transpose_bf16_kernel(const float* __restrict__ src, bf16* __restrict__ dst, int K, int N)
{
    __shared__ float tile[32][33];
    const long boff = (long)blockIdx.z * K * N;
    src += boff; dst += boff;
    const int n0 = blockIdx.x * 32, k0 = blockIdx.y * 32;
    const int tx = threadIdx.x & 31, ty = threadIdx.x >> 5;
#pragma unroll
    for (int j = 0; j < 32; j += 8)
        tile[ty + j][tx] = src[(long)(k0 + ty + j) * N + n0 + tx];
    __syncthreads();
#pragma unroll
    for (int j = 0; j < 32; j += 8)
        dst[(long)(n0 + ty + j) * K + k0 + tx] = __float2bfloat16(tile[tx][ty + j]);
}

__global__ __launch_bounds__(256)
void cvt_kernel(const float* __restrict__ src, bf16* __restrict__ dst, long n4)
{
    const long i = (long)blockIdx.x * 256 + threadIdx.x;
    if (i >= n4) return;
    const float4 vv = *(const float4*)(src + i * 4);
    bf16 t[4] = {__float2bfloat16(vv.x), __float2bfloat16(vv.y),
                 __float2bfloat16(vv.z), __float2bfloat16(vv.w)};
    *(uint2*)(dst + i * 4) = *(const uint2*)t;
}

// b_a[n] = bo[n] + sum_j bv[j] * wo[j][n]
__global__ __launch_bounds__(256)
void ba_kernel(const float* __restrict__ bv, const float* __restrict__ wo,
               const float* __restrict__ bo, float* __restrict__ ba)
{
    const int n = blockIdx.x * 256 + threadIdx.x;
    float s = bo[n];
    for (int j = 0; j < DM; j++) s += bv[j] * wo[(long)j * DM + n];
    ba[n] = s;
}

extern "C" void kernel_launch(void* const* d_in, const int* in_sizes, int n_in,
                              void* d_out, int out_size, void* d_ws, size_t ws_size,
                              hipStream_t stream)
{
    const float* x       = (const float*)d_in[0];
    const float* w_in    = (const float*)d_in[1];
    const float* b_in    = (const float*)d_in[2];
    const float* wv      = (const float*)d_in[7];
    const float* bv      = (const float*)d_in[8];
    const float* wo      = (const float*)d_in[9];
    const float* bo      = (const float*)d_in[10];
    const float* conv1_w = (const float*)d_in[11];
    const float* conv1_b = (const float*)d_in[12];
    const float* conv2_w = (const float*)d_in[13];
    const float* conv2_b = (const float*)d_in[14];
    const float* n1_g    = (const float*)d_in[15];
    const float* n1_b    = (const float*)d_in[16];
    const float* n2_g    = (const float*)d_in[17];
    const float* n2_b    = (const float*)d_in[18];
    const float* norm_g  = (const float*)d_in[19];
    const float* norm_b  = (const float*)d_in[20];
    const float* w1      = (const float*)d_in[21];
    const float* b1      = (const float*)d_in[22];
    const float* w2      = (const float*)d_in[23];
    const float* b2      = (const float*)d_in[24];
    float* out = (float*)d_out;

    char* ws = (char*)d_ws;
    size_t off = 0;
    auto alloc = [&](size_t bytes) {
        char* p = ws + off;
        off += (bytes + 255) & ~(size_t)255;
        return p;
    };
    bf16*  xbf  = (bf16*) alloc((size_t)B_ROWS * DM * 2);
    float* h    = (float*)alloc((size_t)B_ROWS * DM * 4);
    bf16*  hbf  = (bf16*) alloc((size_t)B_ROWS * DM * 2);
    bf16*  tmpb = (bf16*) alloc((size_t)B_ROWS * DM * 2);
    bf16*  y1   = (bf16*) alloc((size_t)B_ROWS * DFF * 2);
    bf16*  winT = (bf16*) alloc((size_t)DM * DM * 2);
    bf16*  woT  = (bf16*) alloc((size_t)DM * DM * 2);
    bf16*  wvbf = (bf16*) alloc((size_t)DM * DM * 2);
    bf16*  WaT  = (bf16*) alloc((size_t)DM * DM * 2);
    float* ba   = (float*)alloc((size_t)DM * 4);
    bf16*  c1T  = (bf16*) alloc((size_t)3 * DFF * DM * 2);
    bf16*  c2T  = (bf16*) alloc((size_t)3 * DM * DFF * 2);
    bf16*  w1T  = (bf16*) alloc((size_t)DFF * DM * 2);
    bf16*  w2T  = (bf16*) alloc((size_t)DOUT * DFF * 2);

    dim3 blk(256);

    // ---- prep ----
    cvt_kernel<<<(B_ROWS * DM / 4 + 255) / 256, blk, 0, stream>>>(x, xbf, (long)B_ROWS * DM / 4);
    cvt_kernel<<<(DM * DM / 4 + 255) / 256, blk, 0, stream>>>(wv, wvbf, (long)DM * DM / 4);
    transpose_bf16_kernel<<<dim3(DM / 32, DM / 32, 1), blk, 0, stream>>>(w_in, winT, DM, DM);
    transpose_bf16_kernel<<<dim3(DM / 32, DM / 32, 1), blk, 0, stream>>>(wo, woT, DM, DM);
    transpose_bf16_kernel<<<dim3(DFF / 32, DM / 32, 3), blk, 0, stream>>>(conv1_w, c1T, DM, DFF);
    transpose_bf16_kernel<<<dim3(DM / 32, DFF / 32, 3), blk, 0, stream>>>(conv2_w, c2T, DFF, DM);
    transpose_bf16_kernel<<<dim3(DFF / 32, DM / 32, 1), blk, 0, stream>>>(w1, w1T, DM, DFF);
    transpose_bf16_kernel<<<dim3(DOUT / 32, DFF / 32, 1), blk, 0, stream>>>(w2, w2T, DFF, DOUT);
    ba_kernel<<<2, blk, 0, stream>>>(bv, wo, bo, ba);
    gemm_kernel<false, false, true><<<dim3(4, 4), blk, 0, stream>>>(
        woT, wvbf, nullptr, nullptr, WaT, DM, DM, DM);

    // ---- h0 = x @ w_in + b_in ----
    gemm_kernel<false, true, true><<<dim3(4, 128), blk, 0, stream>>>(
        xbf, winT, b_in, h, hbf, B_ROWS, DM, DM);

    // ---- encoder layers ----
    for (int i = 0; i < 3; i++) {
        gemm_kernel<false, false, true><<<dim3(4, 128), blk, 0, stream>>>(
            hbf, WaT, ba, nullptr, tmpb, B_ROWS, DM, DM);
        ln_kernel<true, true><<<B_ROWS / 4, blk, 0, stream>>>(
            h, tmpb, n1_g + i * DM, n1_b + i * DM, h, hbf);
        // y1 = gelu(hbf @ conv1 + b)  -- 8-phase 256^2 kernel
        gemm256_gelu_kernel<<<dim3(DFF / 256, B_ROWS / 256), dim3(512), 0, stream>>>(
            hbf, c1T + (size_t)i * DFF * DM, conv1_b + i * DFF, y1, B_ROWS, DFF, DM);
        gemm_kernel<false, false, true><<<dim3(4, 128), blk, 0, stream>>>(
            y1, c2T + (size_t)i * DM * DFF, conv2_b + i * DM, nullptr, tmpb, B_ROWS, DM, DFF);
        ln_kernel<true, true><<<B_ROWS / 4, blk, 0, stream>>>(
            h, tmpb, n2_g + i * DM, n2_b + i * DM, h, hbf);
    }

    // ---- final norm + head ----
    ln_kernel<false, false><<<B_ROWS / 4, blk, 0, stream>>>(
        h, nullptr, norm_g, norm_b, nullptr, hbf);
    gemm256_gelu_kernel<<<dim3(DFF / 256, B_ROWS / 256), dim3(512), 0, stream>>>(
        hbf, w1T, b1, y1, B_ROWS, DFF, DM);
    gemm_kernel<false, true, false><<<dim3(2, 128), blk, 0, stream>>>(
        y1, w2T, b2, out, nullptr, B_ROWS, DOUT, DFF);
}

// Round 9
// 776.784 us; speedup vs baseline: 1.0467x; 1.0467x over previous
//
#include <hip/hip_runtime.h>
#include <hip/hip_bf16.h>
#include <math.h>

#define B_ROWS 16384
#define DM 512
#define DFF 2048
#define DOUT 256
#define EPSV 1e-5f

typedef __hip_bfloat16 bf16;
typedef __attribute__((ext_vector_type(8))) short short8;
typedef __attribute__((ext_vector_type(4))) float f32x4;

// tanh-form GELU: max abs err ~3e-4 vs exact erf form; attenuated to <3e-4
// absolute in final output through the 0.02-scale downstream weights.
__device__ __forceinline__ float gelu_f(float x) {
    float u = x * x * x;
    float z = 0.7978845608f * x + 0.0356774081f * u;
    z = fminf(z, 15.0f);                       // avoid exp overflow -> nan
    float e = __expf(2.0f * z);                // e^(2z)
    return 0.5f * x * (1.0f + (e - 1.0f) / (e + 1.0f));
}

__device__ __forceinline__ float bf2f(short s) {
    return __uint_as_float(((unsigned int)(unsigned short)s) << 16);
}

__device__ __forceinline__ void gload16(const void* g, void* l) {
    __builtin_amdgcn_global_load_lds((const __attribute__((address_space(1))) void*)g,
                                     (__attribute__((address_space(3))) void*)l, 16, 0, 0);
}

// bijective XCD swizzle; requires nwg % 8 == 0 (all our grids satisfy this)
__device__ __forceinline__ int xcd_swz(int bid, int nwg) {
    const int cpx = nwg >> 3;
    return (bid & 7) * cpx + (bid >> 3);
}

// ============================================================================
// 128x128 2-phase GEMM (measured best) — bf16 in, fp32 accum.
// ============================================================================
template<bool GELU, bool OUTF, bool OUTB>
__global__ __launch_bounds__(256, 2)
void gemm_kernel(const bf16* __restrict__ A, const bf16* __restrict__ BT,
                 const float* __restrict__ bias,
                 float* __restrict__ Cf, bf16* __restrict__ Cb,
                 int M, int N, int K)
{
    __shared__ __align__(16) bf16 lA[2][128 * 32];
    __shared__ __align__(16) bf16 lB[2][128 * 32];

    const int t    = threadIdx.x;
    const int lane = t & 63;
    const int w    = t >> 6;
    const int wr   = w >> 1, wc = w & 1;
    const int fr   = lane & 15, kg = lane >> 4;

    int bid = xcd_swz(blockIdx.y * gridDim.x + blockIdx.x, gridDim.x * gridDim.y);
    const int bx = bid % gridDim.x, by = bid / gridDim.x;
    const long bm = (long)by * 128;
    const long bn = (long)bx * 128;

    const int lr = t >> 2;
    const int lc = (t & 3) * 8;

    const bf16* Ag0 = A + (bm + lr) * (long)K + lc;
    const bf16* Ag1 = Ag0 + 64L * K;
    const bf16* Bg0 = BT + (bn + lr) * (long)K + lc;
    const bf16* Bg1 = Bg0 + 64L * K;

    f32x4 acc[4][4];
#pragma unroll
    for (int i = 0; i < 4; i++)
#pragma unroll
        for (int j = 0; j < 4; j++) acc[i][j] = (f32x4){0.f, 0.f, 0.f, 0.f};

    const int nk = K >> 5;

    gload16(Ag0, &lA[0][t * 8]);
    gload16(Ag1, &lA[0][2048 + t * 8]);
    gload16(Bg0, &lB[0][t * 8]);
    gload16(Bg1, &lB[0][2048 + t * 8]);
    Ag0 += 32; Ag1 += 32; Bg0 += 32; Bg1 += 32;
    __syncthreads();

    int cur = 0;
    for (int kt = 0; kt < nk; ++kt) {
        if (kt + 1 < nk) {
            const int nxt = cur ^ 1;
            gload16(Ag0, &lA[nxt][t * 8]);
            gload16(Ag1, &lA[nxt][2048 + t * 8]);
            gload16(Bg0, &lB[nxt][t * 8]);
            gload16(Bg1, &lB[nxt][2048 + t * 8]);
            Ag0 += 32; Ag1 += 32; Bg0 += 32; Bg1 += 32;
        }

        short8 af[4], bv[4];
#pragma unroll
        for (int m = 0; m < 4; m++)
            af[m] = *(const short8*)(&lA[cur][(wr * 64 + m * 16 + fr) * 32 + kg * 8]);
#pragma unroll
        for (int n = 0; n < 4; n++)
            bv[n] = *(const short8*)(&lB[cur][(wc * 64 + n * 16 + fr) * 32 + kg * 8]);
#pragma unroll
        for (int m = 0; m < 4; m++)
#pragma unroll
            for (int n = 0; n < 4; n++)
                acc[m][n] = __builtin_amdgcn_mfma_f32_16x16x32_bf16(af[m], bv[n], acc[m][n], 0, 0, 0);

        __syncthreads();
        cur ^= 1;
    }

    // epilogue: C row = kg*4 + reg (+m*16), col = fr (+n*16)  [verified m89/m91]
#pragma unroll
    for (int m = 0; m < 4; m++) {
        const long row0 = bm + wr * 64 + m * 16 + kg * 4;
#pragma unroll
        for (int n = 0; n < 4; n++) {
            const long col = bn + wc * 64 + n * 16 + fr;
            const float bias_v = bias ? bias[col] : 0.0f;
#pragma unroll
            for (int r = 0; r < 4; r++) {
                float v = acc[m][n][r] + bias_v;
                if (GELU) v = gelu_f(v);
                const long idx = (row0 + r) * (long)N + col;
                if (OUTF) Cf[idx] = v;
                if (OUTB) Cb[idx] = __float2bfloat16(v);
            }
        }
    }
}

// LayerNorm over last dim (512). bf16 spine: reads bf16 x (+ bf16 add), fp32
// math, writes bf16 (in-place on x is safe: each thread reads its own 8 elems
// before writing them). One wave per row, 4 rows/block.
template<bool HASADD>
__global__ __launch_bounds__(256)
void ln_kernel(const bf16* __restrict__ x, const bf16* __restrict__ add,
               const float* __restrict__ g, const float* __restrict__ bb,
               bf16* __restrict__ outb)
{
    const int w    = threadIdx.x >> 6;
    const int lane = threadIdx.x & 63;
    const long row = (long)blockIdx.x * 4 + w;
    const int c0   = lane * 8;

    short8 xv = *(const short8*)(x + row * DM + c0);
    float v[8];
#pragma unroll
    for (int j = 0; j < 8; j++) v[j] = bf2f(xv[j]);
    if (HASADD) {
        short8 ad = *(const short8*)(add + row * DM + c0);
#pragma unroll
        for (int j = 0; j < 8; j++) v[j] += bf2f(ad[j]);
    }
    float s = 0.f;
#pragma unroll
    for (int j = 0; j < 8; j++) s += v[j];
#pragma unroll
    for (int off = 32; off > 0; off >>= 1) s += __shfl_xor(s, off);
    const float mean = s * (1.0f / 512.0f);

    float q = 0.f;
#pragma unroll
    for (int j = 0; j < 8; j++) { v[j] -= mean; q += v[j] * v[j]; }
#pragma unroll
    for (int off = 32; off > 0; off >>= 1) q += __shfl_xor(q, off);
    const float rstd = rsqrtf(q * (1.0f / 512.0f) + EPSV);

    float4 g0 = *(const float4*)(g + c0);
    float4 g1 = *(const float4*)(g + c0 + 4);
    float4 b0 = *(const float4*)(bb + c0);
    float4 b1 = *(const float4*)(bb + c0 + 4);
    float y[8];
    y[0] = v[0] * rstd * g0.x + b0.x; y[1] = v[1] * rstd * g0.y + b0.y;
    y[2] = v[2] * rstd * g0.z + b0.z; y[3] = v[3] * rstd * g0.w + b0.w;
    y[4] = v[4] * rstd * g1.x + b1.x; y[5] = v[5] * rstd * g1.y + b1.y;
    y[6] = v[6] * rstd * g1.z + b1.z; y[7] = v[7] * rstd * g1.w + b1.w;

    bf16 tmpb[8];
#pragma unroll
    for (int j = 0; j < 8; j++) tmpb[j] = __float2bfloat16(y[j]);
    *(uint4*)(outb + row * DM + c0) = *(const uint4*)tmpb;
}

// src (K x N fp32, batched) -> dst (N x K bf16, batched)
__global__ __launch_bounds__(256)
void transpose_bf16_kernel(const float* __restrict__ src, bf16* __restrict__ dst, int K, int N)
{
    __shared__ float tile[32][33];
    const long boff = (long)blockIdx.z * K * N;
    src += boff; dst += boff;
    const int n0 = blockIdx.x * 32, k0 = blockIdx.y * 32;
    const int tx = threadIdx.x & 31, ty = threadIdx.x >> 5;
#pragma unroll
    for (int j = 0; j < 32; j += 8)
        tile[ty + j][tx] = src[(long)(k0 + ty + j) * N + n0 + tx];
    __syncthreads();
#pragma unroll
    for (int j = 0; j < 32; j += 8)
        dst[(long)(n0 + ty + j) * K + k0 + tx] = __float2bfloat16(tile[tx][ty + j]);
}

__global__ __launch_bounds__(256)
void cvt_kernel(const float* __restrict__ src, bf16* __restrict__ dst, long n4)
{
    const long i = (long)blockIdx.x * 256 + threadIdx.x;
    if (i >= n4) return;
    const float4 vv = *(const float4*)(src + i * 4);
    bf16 t[4] = {__float2bfloat16(vv.x), __float2bfloat16(vv.y),
                 __float2bfloat16(vv.z), __float2bfloat16(vv.w)};
    *(uint2*)(dst + i * 4) = *(const uint2*)t;
}

// b_a[n] = bo[n] + sum_j bv[j] * wo[j][n]
__global__ __launch_bounds__(256)
void ba_kernel(const float* __restrict__ bv, const float* __restrict__ wo,
               const float* __restrict__ bo, float* __restrict__ ba)
{
    const int n = blockIdx.x * 256 + threadIdx.x;
    float s = bo[n];
    for (int j = 0; j < DM; j++) s += bv[j] * wo[(long)j * DM + n];
    ba[n] = s;
}

extern "C" void kernel_launch(void* const* d_in, const int* in_sizes, int n_in,
                              void* d_out, int out_size, void* d_ws, size_t ws_size,
                              hipStream_t stream)
{
    const float* x       = (const float*)d_in[0];
    const float* w_in    = (const float*)d_in[1];
    const float* b_in    = (const float*)d_in[2];
    const float* wv      = (const float*)d_in[7];
    const float* bv      = (const float*)d_in[8];
    const float* wo      = (const float*)d_in[9];
    const float* bo      = (const float*)d_in[10];
    const float* conv1_w = (const float*)d_in[11];
    const float* conv1_b = (const float*)d_in[12];
    const float* conv2_w = (const float*)d_in[13];
    const float* conv2_b = (const float*)d_in[14];
    const float* n1_g    = (const float*)d_in[15];
    const float* n1_b    = (const float*)d_in[16];
    const float* n2_g    = (const float*)d_in[17];
    const float* n2_b    = (const float*)d_in[18];
    const float* norm_g  = (const float*)d_in[19];
    const float* norm_b  = (const float*)d_in[20];
    const float* w1      = (const float*)d_in[21];
    const float* b1      = (const float*)d_in[22];
    const float* w2      = (const float*)d_in[23];
    const float* b2      = (const float*)d_in[24];
    float* out = (float*)d_out;

    char* ws = (char*)d_ws;
    size_t off = 0;
    auto alloc = [&](size_t bytes) {
        char* p = ws + off;
        off += (bytes + 255) & ~(size_t)255;
        return p;
    };
    bf16*  xbf  = (bf16*) alloc((size_t)B_ROWS * DM * 2);
    bf16*  hbf  = (bf16*) alloc((size_t)B_ROWS * DM * 2);
    bf16*  tmpb = (bf16*) alloc((size_t)B_ROWS * DM * 2);
    bf16*  y1   = (bf16*) alloc((size_t)B_ROWS * DFF * 2);
    bf16*  winT = (bf16*) alloc((size_t)DM * DM * 2);
    bf16*  woT  = (bf16*) alloc((size_t)DM * DM * 2);
    bf16*  wvbf = (bf16*) alloc((size_t)DM * DM * 2);
    bf16*  WaT  = (bf16*) alloc((size_t)DM * DM * 2);
    float* ba   = (float*)alloc((size_t)DM * 4);
    bf16*  c1T  = (bf16*) alloc((size_t)3 * DFF * DM * 2);
    bf16*  c2T  = (bf16*) alloc((size_t)3 * DM * DFF * 2);
    bf16*  w1T  = (bf16*) alloc((size_t)DFF * DM * 2);
    bf16*  w2T  = (bf16*) alloc((size_t)DOUT * DFF * 2);

    dim3 blk(256);

    // ---- prep ----
    cvt_kernel<<<(B_ROWS * DM / 4 + 255) / 256, blk, 0, stream>>>(x, xbf, (long)B_ROWS * DM / 4);
    cvt_kernel<<<(DM * DM / 4 + 255) / 256, blk, 0, stream>>>(wv, wvbf, (long)DM * DM / 4);
    transpose_bf16_kernel<<<dim3(DM / 32, DM / 32, 1), blk, 0, stream>>>(w_in, winT, DM, DM);
    transpose_bf16_kernel<<<dim3(DM / 32, DM / 32, 1), blk, 0, stream>>>(wo, woT, DM, DM);
    transpose_bf16_kernel<<<dim3(DFF / 32, DM / 32, 3), blk, 0, stream>>>(conv1_w, c1T, DM, DFF);
    transpose_bf16_kernel<<<dim3(DM / 32, DFF / 32, 3), blk, 0, stream>>>(conv2_w, c2T, DFF, DM);
    transpose_bf16_kernel<<<dim3(DFF / 32, DM / 32, 1), blk, 0, stream>>>(w1, w1T, DM, DFF);
    transpose_bf16_kernel<<<dim3(DOUT / 32, DFF / 32, 1), blk, 0, stream>>>(w2, w2T, DFF, DOUT);
    ba_kernel<<<2, blk, 0, stream>>>(bv, wo, bo, ba);
    gemm_kernel<false, false, true><<<dim3(4, 4), blk, 0, stream>>>(
        woT, wvbf, nullptr, nullptr, WaT, DM, DM, DM);

    // ---- h0 = x @ w_in + b_in (bf16 spine only) ----
    gemm_kernel<false, false, true><<<dim3(4, 128), blk, 0, stream>>>(
        xbf, winT, b_in, nullptr, hbf, B_ROWS, DM, DM);

    // ---- encoder layers (attn collapsed; bf16 residual spine) ----
    for (int i = 0; i < 3; i++) {
        // tmpb = hbf @ Wa + ba
        gemm_kernel<false, false, true><<<dim3(4, 128), blk, 0, stream>>>(
            hbf, WaT, ba, nullptr, tmpb, B_ROWS, DM, DM);
        // hbf = LN1(hbf + tmpb)   (in-place)
        ln_kernel<true><<<B_ROWS / 4, blk, 0, stream>>>(
            hbf, tmpb, n1_g + i * DM, n1_b + i * DM, hbf);
        // y1 = gelu(hbf @ conv1 + b)
        gemm_kernel<true, false, true><<<dim3(16, 128), blk, 0, stream>>>(
            hbf, c1T + (size_t)i * DFF * DM, conv1_b + i * DFF, nullptr, y1, B_ROWS, DFF, DM);
        // tmpb = y1 @ conv2 + b
        gemm_kernel<false, false, true><<<dim3(4, 128), blk, 0, stream>>>(
            y1, c2T + (size_t)i * DM * DFF, conv2_b + i * DM, nullptr, tmpb, B_ROWS, DM, DFF);
        // hbf = LN2(hbf + tmpb)
        ln_kernel<true><<<B_ROWS / 4, blk, 0, stream>>>(
            hbf, tmpb, n2_g + i * DM, n2_b + i * DM, hbf);
    }

    // ---- final norm + head ----
    ln_kernel<false><<<B_ROWS / 4, blk, 0, stream>>>(
        hbf, nullptr, norm_g, norm_b, hbf);
    gemm_kernel<true, false, true><<<dim3(16, 128), blk, 0, stream>>>(
        hbf, w1T, b1, nullptr, y1, B_ROWS, DFF, DM);
    gemm_kernel<false, true, false><<<dim3(2, 128), blk, 0, stream>>>(
        y1, w2T, b2, out, nullptr, B_ROWS, DOUT, DFF);
}